// Round 1
// baseline (231.700 us; speedup 1.0000x reference)
//
#include <hip/hip_runtime.h>
#include <hip/hip_bf16.h>
#include <stdint.h>

#define TT 4096
#define DM 128
#define DIN 256
#define NB 4

typedef __attribute__((ext_vector_type(4))) float f32x4;
typedef __attribute__((ext_vector_type(8))) short s16x8;
typedef __attribute__((ext_vector_type(4))) short s16x4;

__device__ __forceinline__ unsigned short f2bf(float f) {
    union { float f; unsigned int u; } v; v.f = f;
    return (unsigned short)((v.u + 0x7FFFu + ((v.u >> 16) & 1u)) >> 16);
}
__device__ __forceinline__ float bf2f(unsigned short h) {
    union { unsigned int u; float f; } v; v.u = ((unsigned int)h) << 16;
    return v.f;
}

// ---------------- kernel 0: W (256x128 f32) -> Wt bf16 [3][128][256] ----------------
__global__ __launch_bounds__(256) void k_wt(const float* __restrict__ Wq,
                                            const float* __restrict__ Wk,
                                            const float* __restrict__ Wv,
                                            unsigned short* __restrict__ Wtb) {
    int tid = blockIdx.x * 256 + threadIdx.x;   // 0..98303
    int m = tid >> 15;
    int r = tid & 32767;
    int n = r >> 8;      // 0..127
    int k = r & 255;     // 0..255
    const float* W = (m == 0) ? Wq : (m == 1) ? Wk : Wv;
    Wtb[(size_t)tid] = f2bf(W[k * DM + n]);     // Wtb[m][n][k]
}

// ---------------- kernel 1: projections x@W+b -> Q/K/V bf16 [16384][128] ------------
__global__ __launch_bounds__(256) void k_proj(const float* __restrict__ x,
        const float* __restrict__ bq, const float* __restrict__ bk, const float* __restrict__ bv,
        const unsigned short* __restrict__ Wtb,
        unsigned short* __restrict__ Qb, unsigned short* __restrict__ Kb,
        unsigned short* __restrict__ Vb) {
    __shared__ __align__(16) unsigned short wt[DM][40];  // [128][32+8] per k-step
    __shared__ __align__(16) unsigned short xl[64][40];
    int m = blockIdx.x >> 8;          // 0=q 1=k 2=v
    int tile = blockIdx.x & 255;
    int rowbase = tile * 64;
    int i = threadIdx.x;
    int w = i >> 6, l = i & 63;
    int lg = l >> 4, ll = l & 15;
    const float* bias = (m == 0) ? bq : (m == 1) ? bk : bv;
    unsigned short* out = (m == 0) ? Qb : (m == 1) ? Kb : Vb;
    const unsigned short* wsrc = Wtb + (size_t)m * DM * DIN;

    f32x4 acc[8];
    for (int n = 0; n < 8; n++) acc[n] = (f32x4){0.f, 0.f, 0.f, 0.f};

    for (int kk = 0; kk < 8; kk++) {
        int k0 = kk * 32;
        // stage W chunk: 128 rows x 4 chunks of 8 bf16
        for (int t = 0; t < 2; t++) {
            int idx = i + t * 256;
            int row = idx >> 2, c8 = idx & 3;
            s16x8 v = *(const s16x8*)(wsrc + (size_t)row * DIN + k0 + c8 * 8);
            *(s16x8*)(&wt[row][c8 * 8]) = v;
        }
        // stage x chunk: 64 rows x 32 f32 -> bf16
        for (int t = 0; t < 2; t++) {
            int idx = i + t * 256;
            int row = idx >> 3, c4 = idx & 7;
            f32x4 v = *(const f32x4*)(x + (size_t)(rowbase + row) * DIN + k0 + c4 * 4);
            s16x4 h;
            for (int j = 0; j < 4; j++) h[j] = (short)f2bf(v[j]);
            *(s16x4*)(&xl[row][c4 * 4]) = h;
        }
        __syncthreads();
        s16x8 a = *(const s16x8*)(&xl[w * 16 + ll][lg * 8]);
        for (int n = 0; n < 8; n++) {
            s16x8 b = *(const s16x8*)(&wt[n * 16 + ll][lg * 8]);
            acc[n] = __builtin_amdgcn_mfma_f32_16x16x32_bf16(a, b, acc[n], 0, 0, 0);
        }
        __syncthreads();
    }
    for (int n = 0; n < 8; n++) {
        int col = n * 16 + ll;
        float bv_ = bias[col];
        for (int j = 0; j < 4; j++) {
            int row = rowbase + w * 16 + lg * 4 + j;
            out[(size_t)row * DM + col] = f2bf(acc[n][j] + bv_);
        }
    }
}

// ---------------- kernel 2: V [b][t][d] -> Vt [b][d][t] (bf16) ----------------------
__global__ __launch_bounds__(256) void k_vt(const unsigned short* __restrict__ Vb,
                                            unsigned short* __restrict__ Vtb) {
    __shared__ __align__(16) unsigned short tile[64][72];
    int bid = blockIdx.x;           // 512 blocks
    int b = bid >> 7;
    int rem = bid & 127;
    int tI = rem >> 1, dI = rem & 1;
    int t0 = tI * 64, d0 = dI * 64;
    int i = threadIdx.x;
    for (int t = 0; t < 2; t++) {
        int idx = i + t * 256;
        int r = idx >> 3, c8 = idx & 7;
        s16x8 v = *(const s16x8*)(Vb + ((size_t)(b * TT) + t0 + r) * DM + d0 + c8 * 8);
        *(s16x8*)(&tile[r][c8 * 8]) = v;
    }
    __syncthreads();
    for (int t = 0; t < 2; t++) {
        int idx = i + t * 256;
        int r2 = idx >> 3, c8 = idx & 7;   // r2 = d-index, c8 = t-chunk
        s16x8 v;
        for (int j = 0; j < 8; j++) v[j] = (short)tile[c8 * 8 + j][r2];
        *(s16x8*)(Vtb + ((size_t)b * DM + d0 + r2) * TT + t0 + c8 * 8) = v;
    }
}

// ---------------- kernel 3: attention (scores twice, softmax, attn write, PV) -------
// grid 256 (4 batch x 64 row-tiles of 64), block 512 = 8 waves:
//   wave w: rh=w&3 -> rows rh*16..+16 of the tile, kh=w>>2 -> key half of each 64-key step
__global__ __launch_bounds__(512) void k_attn(const unsigned short* __restrict__ Qb,
        const unsigned short* __restrict__ Kb, const unsigned short* __restrict__ Vtb,
        float* __restrict__ outO, float* __restrict__ outA) {
    __shared__ __align__(16) char smem[45056];
    unsigned short* Kl = (unsigned short*)smem;             // [64][136]
    unsigned short* Vl = (unsigned short*)(smem + 17408);   // [128][72]
    unsigned short* Pl = (unsigned short*)(smem + 35840);   // [64][72]

    int bid = blockIdx.x;
    int id2 = (bid & 7) * 32 + (bid >> 3);   // XCD-contiguous swizzle (bijective, 256%8==0)
    int b = id2 >> 6;
    int rowbase = (id2 & 63) * 64;
    int i = threadIdx.x;
    int w = i >> 6, l = i & 63;
    int rh = w & 3, kh = w >> 2;
    int lg = l >> 4, ll = l & 15;

    const unsigned short* Qrow = Qb + ((size_t)(b * TT) + rowbase) * DM;
    const unsigned short* Krow = Kb + (size_t)(b * TT) * DM;
    const unsigned short* Vtb_b = Vtb + (size_t)b * DM * TT;
    const float scale = 0.08838834764831845f;  // 1/sqrt(128)

    // Q fragments: rows rh*16+ll, k-chunks c*32
    s16x8 qf[4];
    for (int c = 0; c < 4; c++)
        qf[c] = *(const s16x8*)(Qrow + (size_t)(rh * 16 + ll) * DM + c * 32 + lg * 8);

    // ---- phase 1: rowsums of exp(S) ----
    float rs[4] = {0.f, 0.f, 0.f, 0.f};
    for (int s0 = 0; s0 < TT; s0 += 64) {
        for (int t = 0; t < 2; t++) {
            int idx = i + t * 512;
            int row = idx >> 4, c8 = idx & 15;
            s16x8 v = *(const s16x8*)(Krow + (size_t)(s0 + row) * DM + c8 * 8);
            *(s16x8*)(&Kl[row * 136 + c8 * 8]) = v;
        }
        __syncthreads();
        for (int n2 = 0; n2 < 2; n2++) {
            f32x4 acc = (f32x4){0.f, 0.f, 0.f, 0.f};
            int kcol = kh * 32 + n2 * 16 + ll;
            for (int c = 0; c < 4; c++) {
                s16x8 bfr = *(const s16x8*)(&Kl[kcol * 136 + c * 32 + lg * 8]);
                acc = __builtin_amdgcn_mfma_f32_16x16x32_bf16(qf[c], bfr, acc, 0, 0, 0);
            }
            for (int j = 0; j < 4; j++) rs[j] += __expf(acc[j] * scale);
        }
        __syncthreads();
    }
    // reduce over the 16 lanes of each quarter-group (cols), then across key-halves
    for (int mm = 1; mm < 16; mm <<= 1)
        for (int j = 0; j < 4; j++) rs[j] += __shfl_xor(rs[j], mm, 64);
    float* rsx = (float*)Pl;     // [2][4][16] scratch
    if (ll == 0)
        for (int j = 0; j < 4; j++) rsx[(kh * 4 + rh) * 16 + lg * 4 + j] = rs[j];
    __syncthreads();
    float inv[4];
    for (int j = 0; j < 4; j++) {
        float tot = rsx[(0 * 4 + rh) * 16 + lg * 4 + j] + rsx[(1 * 4 + rh) * 16 + lg * 4 + j];
        inv[j] = 1.0f / tot;
    }
    __syncthreads();

    // ---- phase 2: recompute S, write attn, accumulate O = P@V ----
    f32x4 oacc[8];
    for (int n = 0; n < 8; n++) oacc[n] = (f32x4){0.f, 0.f, 0.f, 0.f};

    for (int s0 = 0; s0 < TT; s0 += 64) {
        for (int t = 0; t < 2; t++) {
            int idx = i + t * 512;
            int row = idx >> 4, c8 = idx & 15;
            s16x8 v = *(const s16x8*)(Krow + (size_t)(s0 + row) * DM + c8 * 8);
            *(s16x8*)(&Kl[row * 136 + c8 * 8]) = v;
        }
        for (int t = 0; t < 2; t++) {
            int idx = i + t * 512;
            int row = idx >> 3, c8 = idx & 7;
            s16x8 v = *(const s16x8*)(Vtb_b + (size_t)row * TT + s0 + c8 * 8);
            *(s16x8*)(&Vl[row * 72 + c8 * 8]) = v;
        }
        __syncthreads();
        for (int n2 = 0; n2 < 2; n2++) {
            f32x4 acc = (f32x4){0.f, 0.f, 0.f, 0.f};
            int kcol = kh * 32 + n2 * 16 + ll;
            for (int c = 0; c < 4; c++) {
                s16x8 bfr = *(const s16x8*)(&Kl[kcol * 136 + c * 32 + lg * 8]);
                acc = __builtin_amdgcn_mfma_f32_16x16x32_bf16(qf[c], bfr, acc, 0, 0, 0);
            }
            for (int j = 0; j < 4; j++) {
                float p = __expf(acc[j] * scale) * inv[j];
                Pl[(rh * 16 + lg * 4 + j) * 72 + kh * 32 + n2 * 16 + ll] = f2bf(p);
            }
        }
        __syncthreads();
        // PV: wave's 16 rows x its 32-key chunk
        {
            s16x8 af = *(const s16x8*)(&Pl[(rh * 16 + ll) * 72 + kh * 32 + lg * 8]);
            for (int n8 = 0; n8 < 8; n8++) {
                s16x8 bfr = *(const s16x8*)(&Vl[(n8 * 16 + ll) * 72 + kh * 32 + lg * 8]);
                oacc[n8] = __builtin_amdgcn_mfma_f32_16x16x32_bf16(af, bfr, oacc[n8], 0, 0, 0);
            }
        }
        // attn output (f32) from Pl, coalesced
        for (int t = 0; t < 2; t++) {
            int idx = i + t * 512;
            int row = idx >> 4, c4 = idx & 15;
            s16x4 pv = *(const s16x4*)(&Pl[row * 72 + c4 * 4]);
            f32x4 fv;
            for (int j = 0; j < 4; j++) fv[j] = bf2f((unsigned short)pv[j]);
            *(f32x4*)(outA + ((size_t)(b * TT) + rowbase + row) * TT + s0 + c4 * 4) = fv;
        }
        __syncthreads();
    }

    // ---- cross key-half O reduction ----
    float* Osc = (float*)smem;   // [64][128] f32 (aliases Kl/Vl, dead now)
    if (kh == 0) {
        for (int n8 = 0; n8 < 8; n8++)
            for (int j = 0; j < 4; j++) {
                int row = rh * 16 + lg * 4 + j, col = n8 * 16 + ll;
                Osc[row * DM + col] = oacc[n8][j];
            }
    }
    __syncthreads();
    if (kh == 1) {
        for (int n8 = 0; n8 < 8; n8++)
            for (int j = 0; j < 4; j++) {
                int row = rh * 16 + lg * 4 + j, col = n8 * 16 + ll;
                float v = oacc[n8][j] + Osc[row * DM + col];
                outO[((size_t)(b * TT) + rowbase + row) * DM + col] = v;
            }
    }
}

extern "C" void kernel_launch(void* const* d_in, const int* in_sizes, int n_in,
                              void* d_out, int out_size, void* d_ws, size_t ws_size,
                              hipStream_t stream) {
    const float* x  = (const float*)d_in[0];
    const float* Wq = (const float*)d_in[1];
    const float* bq = (const float*)d_in[2];
    const float* Wk = (const float*)d_in[3];
    const float* bk = (const float*)d_in[4];
    const float* Wv = (const float*)d_in[5];
    const float* bv = (const float*)d_in[6];
    float* outO = (float*)d_out;
    float* outA = outO + (size_t)NB * TT * DM;

    char* ws = (char*)d_ws;
    unsigned short* Qb  = (unsigned short*)(ws);
    unsigned short* Kb  = (unsigned short*)(ws + ((size_t)1 << 22));
    unsigned short* Vb  = (unsigned short*)(ws + ((size_t)2 << 22));
    unsigned short* Vtb = (unsigned short*)(ws + ((size_t)3 << 22));
    unsigned short* Wtb = (unsigned short*)(ws + ((size_t)4 << 22));

    k_wt<<<dim3(384), dim3(256), 0, stream>>>(Wq, Wk, Wv, Wtb);
    k_proj<<<dim3(768), dim3(256), 0, stream>>>(x, bq, bk, bv, Wtb, Qb, Kb, Vb);
    k_vt<<<dim3(512), dim3(256), 0, stream>>>(Vb, Vtb);
    k_attn<<<dim3(256), dim3(512), 0, stream>>>(Qb, Kb, Vtb, outO, outA);
}

// Round 2
// 160.639 us; speedup vs baseline: 1.4424x; 1.4424x over previous
//
#include <hip/hip_runtime.h>
#include <hip/hip_bf16.h>
#include <stdint.h>

#define TT 4096
#define DM 128
#define DIN 256
#define NB 4

typedef __attribute__((ext_vector_type(4))) float f32x4;
typedef __attribute__((ext_vector_type(8))) short s16x8;
typedef __attribute__((ext_vector_type(4))) short s16x4;

__device__ __forceinline__ unsigned short f2bf(float f) {
    union { float f; unsigned int u; } v; v.f = f;
    return (unsigned short)((v.u + 0x7FFFu + ((v.u >> 16) & 1u)) >> 16);
}
__device__ __forceinline__ float bf2f(unsigned short h) {
    union { unsigned int u; float f; } v; v.u = ((unsigned int)h) << 16;
    return v.f;
}

// ---------------- kernel 0: W (256x128 f32) -> Wt bf16 [3][128][256] ----------------
__global__ __launch_bounds__(256) void k_wt(const float* __restrict__ Wq,
                                            const float* __restrict__ Wk,
                                            const float* __restrict__ Wv,
                                            unsigned short* __restrict__ Wtb) {
    int tid = blockIdx.x * 256 + threadIdx.x;   // 0..98303
    int m = tid >> 15;
    int r = tid & 32767;
    int n = r >> 8;      // 0..127
    int k = r & 255;     // 0..255
    const float* W = (m == 0) ? Wq : (m == 1) ? Wk : Wv;
    Wtb[(size_t)tid] = f2bf(W[k * DM + n]);     // Wtb[m][n][k]
}

// ---------------- kernel 1: projections x@W+b -> Q/K/V bf16 [16384][128] ------------
__global__ __launch_bounds__(256) void k_proj(const float* __restrict__ x,
        const float* __restrict__ bq, const float* __restrict__ bk, const float* __restrict__ bv,
        const unsigned short* __restrict__ Wtb,
        unsigned short* __restrict__ Qb, unsigned short* __restrict__ Kb,
        unsigned short* __restrict__ Vb) {
    __shared__ __align__(16) unsigned short wt[DM][40];  // [128][32+8] per k-step
    __shared__ __align__(16) unsigned short xl[64][40];
    int m = blockIdx.x >> 8;          // 0=q 1=k 2=v
    int tile = blockIdx.x & 255;
    int rowbase = tile * 64;
    int i = threadIdx.x;
    int w = i >> 6, l = i & 63;
    int lg = l >> 4, ll = l & 15;
    const float* bias = (m == 0) ? bq : (m == 1) ? bk : bv;
    unsigned short* out = (m == 0) ? Qb : (m == 1) ? Kb : Vb;
    const unsigned short* wsrc = Wtb + (size_t)m * DM * DIN;

    f32x4 acc[8];
    for (int n = 0; n < 8; n++) acc[n] = (f32x4){0.f, 0.f, 0.f, 0.f};

    for (int kk = 0; kk < 8; kk++) {
        int k0 = kk * 32;
        for (int t = 0; t < 2; t++) {
            int idx = i + t * 256;
            int row = idx >> 2, c8 = idx & 3;
            s16x8 v = *(const s16x8*)(wsrc + (size_t)row * DIN + k0 + c8 * 8);
            *(s16x8*)(&wt[row][c8 * 8]) = v;
        }
        for (int t = 0; t < 2; t++) {
            int idx = i + t * 256;
            int row = idx >> 3, c4 = idx & 7;
            f32x4 v = *(const f32x4*)(x + (size_t)(rowbase + row) * DIN + k0 + c4 * 4);
            s16x4 h;
            for (int j = 0; j < 4; j++) h[j] = (short)f2bf(v[j]);
            *(s16x4*)(&xl[row][c4 * 4]) = h;
        }
        __syncthreads();
        s16x8 a = *(const s16x8*)(&xl[w * 16 + ll][lg * 8]);
        for (int n = 0; n < 8; n++) {
            s16x8 b = *(const s16x8*)(&wt[n * 16 + ll][lg * 8]);
            acc[n] = __builtin_amdgcn_mfma_f32_16x16x32_bf16(a, b, acc[n], 0, 0, 0);
        }
        __syncthreads();
    }
    for (int n = 0; n < 8; n++) {
        int col = n * 16 + ll;
        float bv_ = bias[col];
        for (int j = 0; j < 4; j++) {
            int row = rowbase + w * 16 + lg * 4 + j;
            out[(size_t)row * DM + col] = f2bf(acc[n][j] + bv_);
        }
    }
}

// ---------------- kernel 2: V [b][t][d] -> Vt [b][d][t] (bf16) ----------------------
__global__ __launch_bounds__(256) void k_vt(const unsigned short* __restrict__ Vb,
                                            unsigned short* __restrict__ Vtb) {
    __shared__ __align__(16) unsigned short tile[64][72];
    int bid = blockIdx.x;           // 512 blocks
    int b = bid >> 7;
    int rem = bid & 127;
    int tI = rem >> 1, dI = rem & 1;
    int t0 = tI * 64, d0 = dI * 64;
    int i = threadIdx.x;
    for (int t = 0; t < 2; t++) {
        int idx = i + t * 256;
        int r = idx >> 3, c8 = idx & 7;
        s16x8 v = *(const s16x8*)(Vb + ((size_t)(b * TT) + t0 + r) * DM + d0 + c8 * 8);
        *(s16x8*)(&tile[r][c8 * 8]) = v;
    }
    __syncthreads();
    for (int t = 0; t < 2; t++) {
        int idx = i + t * 256;
        int r2 = idx >> 3, c8 = idx & 7;   // r2 = d-index, c8 = t-chunk
        s16x8 v;
        for (int j = 0; j < 8; j++) v[j] = (short)tile[c8 * 8 + j][r2];
        *(s16x8*)(Vtb + ((size_t)b * DM + d0 + r2) * TT + t0 + c8 * 8) = v;
    }
}

// ---------------- kernel 3: attention, 32-row tiles, 2 blocks/CU ---------------------
// grid 512 (4 batch x 128 row-tiles of 32), block 512 = 8 waves.
// QK assignment: rh=w&1 (16-row group), kh=w>>1 (16-key quarter of 64-key step).
// PV assignment: r2=w&1 (16-row group), h2=(w>>1)&1 (32-key half), c2=w>>2 (64-col half).
__global__ __launch_bounds__(512) void k_attn(const unsigned short* __restrict__ Qb,
        const unsigned short* __restrict__ Kb, const unsigned short* __restrict__ Vtb,
        float* __restrict__ outO, float* __restrict__ outA) {
    __shared__ __align__(16) char smem[40448];
    unsigned short* Kl = (unsigned short*)smem;             // [64][136]  17408 B
    unsigned short* Vl = (unsigned short*)(smem + 17408);   // [128][72]  18432 B
    unsigned short* Pl = (unsigned short*)(smem + 35840);   // [32][72]    4608 B

    int bid = blockIdx.x;
    int id2 = (bid & 7) * 64 + (bid >> 3);   // XCD-contiguous swizzle (512%8==0, bijective)
    int b = id2 >> 7;                        // batch
    int rowbase = (id2 & 127) * 32;
    int i = threadIdx.x;
    int w = i >> 6, l = i & 63;
    int rh = w & 1, kh = w >> 1;             // QK roles
    int r2 = w & 1, h2 = (w >> 1) & 1, c2 = w >> 2;   // PV roles
    int lg = l >> 4, ll = l & 15;

    const unsigned short* Qrow = Qb + ((size_t)(b * TT) + rowbase) * DM;
    const unsigned short* Krow = Kb + (size_t)(b * TT) * DM;
    const unsigned short* Vtb_b = Vtb + (size_t)b * DM * TT;
    const float scale = 0.08838834764831845f;  // 1/sqrt(128)

    // Q fragments: row rh*16+ll, k-chunks c*32+lg*8
    s16x8 qf[4];
    for (int c = 0; c < 4; c++)
        qf[c] = *(const s16x8*)(Qrow + (size_t)(rh * 16 + ll) * DM + c * 32 + lg * 8);

    // ---- phase 1: rowsums of exp(S) ----
    float rs[4] = {0.f, 0.f, 0.f, 0.f};
    for (int s0 = 0; s0 < TT; s0 += 64) {
        for (int t = 0; t < 2; t++) {
            int idx = i + t * 512;
            int row = idx >> 4, c8 = idx & 15;
            s16x8 v = *(const s16x8*)(Krow + (size_t)(s0 + row) * DM + c8 * 8);
            *(s16x8*)(&Kl[row * 136 + c8 * 8]) = v;
        }
        __syncthreads();
        {
            f32x4 acc = (f32x4){0.f, 0.f, 0.f, 0.f};
            int kcol = kh * 16 + ll;
            for (int c = 0; c < 4; c++) {
                s16x8 bfr = *(const s16x8*)(&Kl[kcol * 136 + c * 32 + lg * 8]);
                acc = __builtin_amdgcn_mfma_f32_16x16x32_bf16(qf[c], bfr, acc, 0, 0, 0);
            }
            for (int j = 0; j < 4; j++) rs[j] += __expf(acc[j] * scale);
        }
        __syncthreads();
    }
    // reduce across the 16 ll-lanes (key dimension within the wave)
    for (int mm = 1; mm < 16; mm <<= 1)
        for (int j = 0; j < 4; j++) rs[j] += __shfl_xor(rs[j], mm, 64);
    float* rsx = (float*)Pl;     // [4 kh][2 rh][16] scratch
    if (ll == 0)
        for (int j = 0; j < 4; j++) rsx[(kh * 2 + rh) * 16 + lg * 4 + j] = rs[j];
    __syncthreads();
    float inv[4];
    for (int j = 0; j < 4; j++) {
        float tot = rsx[(0 * 2 + rh) * 16 + lg * 4 + j] + rsx[(1 * 2 + rh) * 16 + lg * 4 + j]
                  + rsx[(2 * 2 + rh) * 16 + lg * 4 + j] + rsx[(3 * 2 + rh) * 16 + lg * 4 + j];
        inv[j] = 1.0f / tot;
    }

    // ---- phase 2: recompute S, write attn (direct from acc), accumulate O = P@V ----
    f32x4 oacc[4];
    for (int n = 0; n < 4; n++) oacc[n] = (f32x4){0.f, 0.f, 0.f, 0.f};

    for (int s0 = 0; s0 < TT; s0 += 64) {
        for (int t = 0; t < 2; t++) {
            int idx = i + t * 512;
            int row = idx >> 4, c8 = idx & 15;
            s16x8 v = *(const s16x8*)(Krow + (size_t)(s0 + row) * DM + c8 * 8);
            *(s16x8*)(&Kl[row * 136 + c8 * 8]) = v;
        }
        for (int t = 0; t < 2; t++) {
            int idx = i + t * 512;
            int row = idx >> 3, c8 = idx & 7;
            s16x8 v = *(const s16x8*)(Vtb_b + (size_t)row * TT + s0 + c8 * 8);
            *(s16x8*)(&Vl[row * 72 + c8 * 8]) = v;
        }
        __syncthreads();
        {
            f32x4 acc = (f32x4){0.f, 0.f, 0.f, 0.f};
            int kcol = kh * 16 + ll;
            for (int c = 0; c < 4; c++) {
                s16x8 bfr = *(const s16x8*)(&Kl[kcol * 136 + c * 32 + lg * 8]);
                acc = __builtin_amdgcn_mfma_f32_16x16x32_bf16(qf[c], bfr, acc, 0, 0, 0);
            }
            for (int j = 0; j < 4; j++) {
                float p = __expf(acc[j] * scale) * inv[j];
                // attn write, straight from registers (f32); 64B segments per 16 lanes
                outA[((size_t)(b * TT) + rowbase + rh * 16 + lg * 4 + j) * TT
                     + s0 + kh * 16 + ll] = p;
                Pl[(rh * 16 + lg * 4 + j) * 72 + kh * 16 + ll] = f2bf(p);
            }
        }
        __syncthreads();
        // PV: 16 rows x 64 cols over this wave's 32-key half
        {
            s16x8 af = *(const s16x8*)(&Pl[(r2 * 16 + ll) * 72 + h2 * 32 + lg * 8]);
            for (int n8 = 0; n8 < 4; n8++) {
                s16x8 bfr = *(const s16x8*)(&Vl[(c2 * 64 + n8 * 16 + ll) * 72 + h2 * 32 + lg * 8]);
                oacc[n8] = __builtin_amdgcn_mfma_f32_16x16x32_bf16(af, bfr, oacc[n8], 0, 0, 0);
            }
        }
        __syncthreads();
    }

    // ---- cross key-half O reduction (padded stride 132 to avoid bank conflicts) ----
    float* Osc = (float*)smem;   // [32][132] f32 = 16896 B (aliases Kl, dead now)
    if (h2 == 0) {
        for (int n8 = 0; n8 < 4; n8++)
            for (int j = 0; j < 4; j++) {
                int row = r2 * 16 + lg * 4 + j, col = c2 * 64 + n8 * 16 + ll;
                Osc[row * 132 + col] = oacc[n8][j];
            }
    }
    __syncthreads();
    if (h2 == 1) {
        for (int n8 = 0; n8 < 4; n8++)
            for (int j = 0; j < 4; j++) {
                int row = r2 * 16 + lg * 4 + j, col = c2 * 64 + n8 * 16 + ll;
                float v = oacc[n8][j] + Osc[row * 132 + col];
                outO[((size_t)(b * TT) + rowbase + row) * DM + col] = v;
            }
    }
}

extern "C" void kernel_launch(void* const* d_in, const int* in_sizes, int n_in,
                              void* d_out, int out_size, void* d_ws, size_t ws_size,
                              hipStream_t stream) {
    const float* x  = (const float*)d_in[0];
    const float* Wq = (const float*)d_in[1];
    const float* bq = (const float*)d_in[2];
    const float* Wk = (const float*)d_in[3];
    const float* bk = (const float*)d_in[4];
    const float* Wv = (const float*)d_in[5];
    const float* bv = (const float*)d_in[6];
    float* outO = (float*)d_out;
    float* outA = outO + (size_t)NB * TT * DM;

    char* ws = (char*)d_ws;
    unsigned short* Qb  = (unsigned short*)(ws);
    unsigned short* Kb  = (unsigned short*)(ws + ((size_t)1 << 22));
    unsigned short* Vb  = (unsigned short*)(ws + ((size_t)2 << 22));
    unsigned short* Vtb = (unsigned short*)(ws + ((size_t)3 << 22));
    unsigned short* Wtb = (unsigned short*)(ws + ((size_t)4 << 22));

    k_wt<<<dim3(384), dim3(256), 0, stream>>>(Wq, Wk, Wv, Wtb);
    k_proj<<<dim3(768), dim3(256), 0, stream>>>(x, bq, bk, bv, Wtb, Qb, Kb, Vb);
    k_vt<<<dim3(512), dim3(256), 0, stream>>>(Vb, Vtb);
    k_attn<<<dim3(512), dim3(512), 0, stream>>>(Qb, Kb, Vtb, outO, outA);
}

// Round 3
// 132.763 us; speedup vs baseline: 1.7452x; 1.2100x over previous
//
#include <hip/hip_runtime.h>
#include <hip/hip_bf16.h>
#include <stdint.h>

#define TT 4096
#define DM 128
#define DIN 256
#define NB 4

typedef __attribute__((ext_vector_type(4))) float f32x4;
typedef __attribute__((ext_vector_type(8))) short s16x8;
typedef __attribute__((ext_vector_type(4))) short s16x4;

__device__ __forceinline__ unsigned short f2bf(float f) {
    union { float f; unsigned int u; } v; v.f = f;
    return (unsigned short)((v.u + 0x7FFFu + ((v.u >> 16) & 1u)) >> 16);
}

// async global->LDS, 16B per lane, LDS dest = wave-uniform base + lane*16
__device__ __forceinline__ void cp16(const void* g, void* l) {
    __builtin_amdgcn_global_load_lds(
        (__attribute__((address_space(1))) unsigned int*)(size_t)g,
        (__attribute__((address_space(3))) unsigned int*)l, 16, 0, 0);
}

// ---------------- kernel 0: W (256x128 f32) -> Wt bf16 [3][128][256] ----------------
__global__ __launch_bounds__(256) void k_wt(const float* __restrict__ Wq,
                                            const float* __restrict__ Wk,
                                            const float* __restrict__ Wv,
                                            unsigned short* __restrict__ Wtb) {
    int tid = blockIdx.x * 256 + threadIdx.x;
    int m = tid >> 15;
    int r = tid & 32767;
    int n = r >> 8;
    int k = r & 255;
    const float* W = (m == 0) ? Wq : (m == 1) ? Wk : Wv;
    Wtb[(size_t)tid] = f2bf(W[k * DM + n]);
}

// ---------------- kernel 1: projections x@W+b -> Q/K/V bf16 [16384][128] ------------
__global__ __launch_bounds__(256) void k_proj(const float* __restrict__ x,
        const float* __restrict__ bq, const float* __restrict__ bk, const float* __restrict__ bv,
        const unsigned short* __restrict__ Wtb,
        unsigned short* __restrict__ Qb, unsigned short* __restrict__ Kb,
        unsigned short* __restrict__ Vb) {
    __shared__ __align__(16) unsigned short wt[DM][40];
    __shared__ __align__(16) unsigned short xl[64][40];
    int m = blockIdx.x >> 8;
    int tile = blockIdx.x & 255;
    int rowbase = tile * 64;
    int i = threadIdx.x;
    int w = i >> 6, l = i & 63;
    int lg = l >> 4, ll = l & 15;
    const float* bias = (m == 0) ? bq : (m == 1) ? bk : bv;
    unsigned short* out = (m == 0) ? Qb : (m == 1) ? Kb : Vb;
    const unsigned short* wsrc = Wtb + (size_t)m * DM * DIN;

    f32x4 acc[8];
    for (int n = 0; n < 8; n++) acc[n] = (f32x4){0.f, 0.f, 0.f, 0.f};

    for (int kk = 0; kk < 8; kk++) {
        int k0 = kk * 32;
        for (int t = 0; t < 2; t++) {
            int idx = i + t * 256;
            int row = idx >> 2, c8 = idx & 3;
            s16x8 v = *(const s16x8*)(wsrc + (size_t)row * DIN + k0 + c8 * 8);
            *(s16x8*)(&wt[row][c8 * 8]) = v;
        }
        for (int t = 0; t < 2; t++) {
            int idx = i + t * 256;
            int row = idx >> 3, c4 = idx & 7;
            f32x4 v = *(const f32x4*)(x + (size_t)(rowbase + row) * DIN + k0 + c4 * 4);
            s16x4 h;
            for (int j = 0; j < 4; j++) h[j] = (short)f2bf(v[j]);
            *(s16x4*)(&xl[row][c4 * 4]) = h;
        }
        __syncthreads();
        s16x8 a = *(const s16x8*)(&xl[w * 16 + ll][lg * 8]);
        for (int n = 0; n < 8; n++) {
            s16x8 b = *(const s16x8*)(&wt[n * 16 + ll][lg * 8]);
            acc[n] = __builtin_amdgcn_mfma_f32_16x16x32_bf16(a, b, acc[n], 0, 0, 0);
        }
        __syncthreads();
    }
    for (int n = 0; n < 8; n++) {
        int col = n * 16 + ll;
        float bv_ = bias[col];
        for (int j = 0; j < 4; j++) {
            int row = rowbase + w * 16 + lg * 4 + j;
            out[(size_t)row * DM + col] = f2bf(acc[n][j] + bv_);
        }
    }
}

// ---------------- kernel 2: V [b][t][d] -> Vt [b][d][t] (bf16) ----------------------
__global__ __launch_bounds__(256) void k_vt(const unsigned short* __restrict__ Vb,
                                            unsigned short* __restrict__ Vtb) {
    __shared__ __align__(16) unsigned short tile[64][72];
    int bid = blockIdx.x;
    int b = bid >> 7;
    int rem = bid & 127;
    int tI = rem >> 1, dI = rem & 1;
    int t0 = tI * 64, d0 = dI * 64;
    int i = threadIdx.x;
    for (int t = 0; t < 2; t++) {
        int idx = i + t * 256;
        int r = idx >> 3, c8 = idx & 7;
        s16x8 v = *(const s16x8*)(Vb + ((size_t)(b * TT) + t0 + r) * DM + d0 + c8 * 8);
        *(s16x8*)(&tile[r][c8 * 8]) = v;
    }
    __syncthreads();
    for (int t = 0; t < 2; t++) {
        int idx = i + t * 256;
        int r2 = idx >> 3, c8 = idx & 7;
        s16x8 v;
        for (int j = 0; j < 8; j++) v[j] = (short)tile[c8 * 8 + j][r2];
        *(s16x8*)(Vtb + ((size_t)b * DM + d0 + r2) * TT + t0 + c8 * 8) = v;
    }
}

// ---------------- kernel 3: attention --------------------------------------------
// grid 512 (4 batch x 128 row-tiles of 32), block 512 = 8 waves.
// LDS: K bufs [64][128] bf16 (swizzled, granule^=row&7), V bufs [128][64] bf16 (swizzled).
__global__ __launch_bounds__(512) void k_attn(const unsigned short* __restrict__ Qb,
        const unsigned short* __restrict__ Kb, const unsigned short* __restrict__ Vtb,
        float* __restrict__ outO, float* __restrict__ outA) {
    __shared__ __align__(16) char smem[70144];
    // phase2: K: smem + buf*16384 (buf 0/1); V: smem + 32768 + buf*16384
    // phase1: K 3-deep: smem + idx*16384, idx 0..2
    unsigned short* Pl = (unsigned short*)(smem + 65536);   // [32][72] 4608 B

    int bid = blockIdx.x;
    int id2 = (bid & 7) * 64 + (bid >> 3);   // XCD swizzle (512%8==0, bijective)
    int b = id2 >> 7;
    int rowbase = (id2 & 127) * 32;
    int i = threadIdx.x;
    int w = i >> 6, l = i & 63;
    int rh = w & 1, kh = w >> 1;                       // QK roles
    int r2 = w & 1, h2 = (w >> 1) & 1, c2 = w >> 2;    // PV roles
    int lg = l >> 4, ll = l & 15;

    const unsigned short* Qrow = Qb + ((size_t)(b * TT) + rowbase) * DM;
    const unsigned short* Krow = Kb + (size_t)(b * TT) * DM;
    const unsigned short* Vtb_b = Vtb + (size_t)b * DM * TT;
    const float scale = 0.08838834764831845f;  // 1/sqrt(128)

    // staging lane geometry (per wave: 2 chunks of 1KB each for K and V)
    int kch0 = w * 2;                 // K chunk = 4 rows of 256B
    int krow_l = l >> 4;              // row within chunk
    int kg_l = l & 15;                // dest granule
    int vch0 = w * 2;                 // V chunk = 8 rows of 128B
    int vrow_l = l >> 3;
    int vg_l = l & 7;

    // Q fragments
    s16x8 qf[4];
    for (int c = 0; c < 4; c++)
        qf[c] = *(const s16x8*)(Qrow + (size_t)(rh * 16 + ll) * DM + c * 32 + lg * 8);

    int kr = kh * 16 + ll;   // QK: K row this lane reads

    // ================= phase 1: rowsums of exp(S), 3-buf depth-2 pipeline ============
    float rs[4] = {0.f, 0.f, 0.f, 0.f};
    {
        // prologue: stage tiles 0,1
        for (int pt = 0; pt < 2; pt++) {
            char* kbuf = smem + pt * 16384;
            for (int t = 0; t < 2; t++) {
                int ch = kch0 + t;
                int row = pt * 64 + ch * 4 + krow_l;
                int g = kg_l ^ (row & 7);
                cp16(Krow + (size_t)row * DM + g * 8, kbuf + ch * 1024);
            }
        }
        asm volatile("s_waitcnt vmcnt(2)" ::: "memory");
        __builtin_amdgcn_s_barrier();

        int idx = 0;
        for (int t = 0; t < 64; t++) {
            if (t + 2 < 64) {
                int pidx = idx + 2; if (pidx >= 3) pidx -= 3;
                char* kbuf = smem + pidx * 16384;
                int s0n = (t + 2) * 64;
                for (int u = 0; u < 2; u++) {
                    int ch = kch0 + u;
                    int row = ch * 4 + krow_l;
                    int g = kg_l ^ (row & 7);
                    cp16(Krow + (size_t)(s0n + row) * DM + g * 8, kbuf + ch * 1024);
                }
            }
            const char* kb = smem + idx * 16384 + kr * 256;
            f32x4 acc = (f32x4){0.f, 0.f, 0.f, 0.f};
            for (int c = 0; c < 4; c++) {
                s16x8 bfr = *(const s16x8*)(kb + (((c * 4 + lg) ^ (kr & 7)) << 4));
                acc = __builtin_amdgcn_mfma_f32_16x16x32_bf16(qf[c], bfr, acc, 0, 0, 0);
            }
            for (int j = 0; j < 4; j++) rs[j] += __expf(acc[j] * scale);
            asm volatile("s_waitcnt vmcnt(2)" ::: "memory");
            __builtin_amdgcn_s_barrier();
            idx++; if (idx >= 3) idx = 0;
        }
    }
    // reduce across the 16 ll-lanes
    for (int mm = 1; mm < 16; mm <<= 1)
        for (int j = 0; j < 4; j++) rs[j] += __shfl_xor(rs[j], mm, 64);
    float* rsx = (float*)Pl;
    if (ll == 0)
        for (int j = 0; j < 4; j++) rsx[(kh * 2 + rh) * 16 + lg * 4 + j] = rs[j];
    __syncthreads();
    float inv[4];
    for (int j = 0; j < 4; j++) {
        float tot = rsx[(0 * 2 + rh) * 16 + lg * 4 + j] + rsx[(1 * 2 + rh) * 16 + lg * 4 + j]
                  + rsx[(2 * 2 + rh) * 16 + lg * 4 + j] + rsx[(3 * 2 + rh) * 16 + lg * 4 + j];
        inv[j] = 1.0f / tot;
    }
    __syncthreads();

    // ================= phase 2: recompute S, write attn, O = P@V =====================
    f32x4 oacc[4];
    for (int n = 0; n < 4; n++) oacc[n] = (f32x4){0.f, 0.f, 0.f, 0.f};

    // prologue: stage tile 0 into buf 0
    {
        char* kbuf = smem;
        char* vbuf = smem + 32768;
        for (int u = 0; u < 2; u++) {
            int ch = kch0 + u;
            int row = ch * 4 + krow_l;
            int g = kg_l ^ (row & 7);
            cp16(Krow + (size_t)row * DM + g * 8, kbuf + ch * 1024);
        }
        for (int u = 0; u < 2; u++) {
            int ch = vch0 + u;
            int row = ch * 8 + vrow_l;
            int g = vg_l ^ (row & 7);
            cp16(Vtb_b + (size_t)row * TT + g * 8, vbuf + ch * 1024);
        }
    }
    asm volatile("s_waitcnt vmcnt(0)" ::: "memory");
    __builtin_amdgcn_s_barrier();

    int cur = 0;
    for (int t = 0; t < 64; t++) {
        int s0 = t * 64;
        // issue next-tile stage first (counted by vmcnt as oldest)
        if (t < 63) {
            char* kbuf = smem + (cur ^ 1) * 16384;
            char* vbuf = smem + 32768 + (cur ^ 1) * 16384;
            for (int u = 0; u < 2; u++) {
                int ch = kch0 + u;
                int row = ch * 4 + krow_l;
                int g = kg_l ^ (row & 7);
                cp16(Krow + (size_t)(s0 + 64 + row) * DM + g * 8, kbuf + ch * 1024);
            }
            for (int u = 0; u < 2; u++) {
                int ch = vch0 + u;
                int row = ch * 8 + vrow_l;
                int g = vg_l ^ (row & 7);
                cp16(Vtb_b + (size_t)row * TT + s0 + 64 + g * 8, vbuf + ch * 1024);
            }
        }
        // QK^T from K(cur)
        const char* kb = smem + cur * 16384 + kr * 256;
        f32x4 acc = (f32x4){0.f, 0.f, 0.f, 0.f};
        for (int c = 0; c < 4; c++) {
            s16x8 bfr = *(const s16x8*)(kb + (((c * 4 + lg) ^ (kr & 7)) << 4));
            acc = __builtin_amdgcn_mfma_f32_16x16x32_bf16(qf[c], bfr, acc, 0, 0, 0);
        }
        // softmax, attn store (f32, never drained in-loop), P to LDS
        for (int j = 0; j < 4; j++) {
            float p = __expf(acc[j] * scale) * inv[j];
            outA[((size_t)(b * TT) + rowbase + rh * 16 + lg * 4 + j) * TT
                 + s0 + kh * 16 + ll] = p;
            Pl[(rh * 16 + lg * 4 + j) * 72 + kh * 16 + ll] = f2bf(p);
        }
        asm volatile("s_waitcnt lgkmcnt(0)" ::: "memory");
        __builtin_amdgcn_s_barrier();                       // A: P visible
        // PV from P + V(cur)
        {
            s16x8 af = *(const s16x8*)(Pl + (r2 * 16 + ll) * 72 + h2 * 32 + lg * 8);
            const char* vb = smem + 32768 + cur * 16384;
            for (int n8 = 0; n8 < 4; n8++) {
                int vr = c2 * 64 + n8 * 16 + ll;
                s16x8 bfr = *(const s16x8*)(vb + vr * 128 + (((h2 * 4 + lg) ^ (vr & 7)) << 4));
                oacc[n8] = __builtin_amdgcn_mfma_f32_16x16x32_bf16(af, bfr, oacc[n8], 0, 0, 0);
            }
        }
        asm volatile("s_waitcnt vmcnt(4)" ::: "memory");    // stage done; stores may linger
        __builtin_amdgcn_s_barrier();                       // B: next tile ready
        cur ^= 1;
    }

    // ---- cross key-half O reduction (stride 132 = conflict-free) ----
    float* Osc = (float*)smem;   // [32][132] f32, aliases K bufs (dead)
    if (h2 == 0) {
        for (int n8 = 0; n8 < 4; n8++)
            for (int j = 0; j < 4; j++) {
                int row = r2 * 16 + lg * 4 + j, col = c2 * 64 + n8 * 16 + ll;
                Osc[row * 132 + col] = oacc[n8][j];
            }
    }
    __syncthreads();
    if (h2 == 1) {
        for (int n8 = 0; n8 < 4; n8++)
            for (int j = 0; j < 4; j++) {
                int row = r2 * 16 + lg * 4 + j, col = c2 * 64 + n8 * 16 + ll;
                float v = oacc[n8][j] + Osc[row * 132 + col];
                outO[((size_t)(b * TT) + rowbase + row) * DM + col] = v;
            }
    }
}

extern "C" void kernel_launch(void* const* d_in, const int* in_sizes, int n_in,
                              void* d_out, int out_size, void* d_ws, size_t ws_size,
                              hipStream_t stream) {
    const float* x  = (const float*)d_in[0];
    const float* Wq = (const float*)d_in[1];
    const float* bq = (const float*)d_in[2];
    const float* Wk = (const float*)d_in[3];
    const float* bk = (const float*)d_in[4];
    const float* Wv = (const float*)d_in[5];
    const float* bv = (const float*)d_in[6];
    float* outO = (float*)d_out;
    float* outA = outO + (size_t)NB * TT * DM;

    char* ws = (char*)d_ws;
    unsigned short* Qb  = (unsigned short*)(ws);
    unsigned short* Kb  = (unsigned short*)(ws + ((size_t)1 << 22));
    unsigned short* Vb  = (unsigned short*)(ws + ((size_t)2 << 22));
    unsigned short* Vtb = (unsigned short*)(ws + ((size_t)3 << 22));
    unsigned short* Wtb = (unsigned short*)(ws + ((size_t)4 << 22));

    k_wt<<<dim3(384), dim3(256), 0, stream>>>(Wq, Wk, Wv, Wtb);
    k_proj<<<dim3(768), dim3(256), 0, stream>>>(x, bq, bk, bv, Wtb, Qb, Kb, Vb);
    k_vt<<<dim3(512), dim3(256), 0, stream>>>(Vb, Vtb);
    k_attn<<<dim3(512), dim3(512), 0, stream>>>(Qb, Kb, Vtb, outO, outA);
}